// Round 7
// baseline (298.250 us; speedup 1.0000x reference)
//
#include <hip/hip_runtime.h>
#include <hip/hip_bf16.h>

#define D_MODEL 1024
#define NH 16
#define DH 64
#define S_LEN 2048
#define BATCH 2
// Q folded scale: 1/sqrt(64) * log2(e) so softmax uses exp2 with m == 0.
#define QSCALE (0.125f * 1.44269504088896f)

#define KV_HSTRIDE (S_LEN * DH)           // ushorts per head slab
#define WS_V_OFF   (NH * KV_HSTRIDE)      // V^T offset within a batch slab
#define KVB_WORDS  (2 * NH * KV_HSTRIDE)  // ushorts per batch K+V slab (8.39 MB)
#define MB_WORDS   ((S_LEN / 64) * S_LEN) // uint64 mask words per batch (512 KB)
#define KTILE 128
#define NT (S_LEN / KTILE)
#define X_ELEMS (BATCH * S_LEN * D_MODEL)   // 4.19M per tensor
#define W_ELEMS (D_MODEL * D_MODEL)         // 1.05M per tensor
#define KSTR 88                             // Kt row stride (176 B, 16B-aligned)
#define VSTR 136                            // Vt row stride (sb fallback only)

typedef __attribute__((ext_vector_type(8))) short bf16x8;
typedef __attribute__((ext_vector_type(4))) float f32x4;
typedef __attribute__((ext_vector_type(2))) unsigned int u32x2;

static __device__ inline unsigned short f2bf(float f) {
    union { float f; unsigned u; } v; v.f = f;
    unsigned r = v.u + 0x7fffu + ((v.u >> 16) & 1u);
    return (unsigned short)(r >> 16);
}
static __device__ inline unsigned cvt2(float a, float b) {
    union { __hip_bfloat162 h2; unsigned u; } cv;
    cv.h2 = __float22bfloat162_rn(make_float2(a, b));
    return cv.u;
}
static __device__ inline bf16x8 pack8(f32x4 a, f32x4 b) {
    union { bf16x8 v; unsigned u[4]; } r;
    r.u[0] = cvt2(a[0], a[1]); r.u[1] = cvt2(a[2], a[3]);
    r.u[2] = cvt2(b[0], b[1]); r.u[3] = cvt2(b[2], b[3]);
    return r.v;
}
static __device__ inline bf16x8 cvt8(const float* __restrict__ p) {
    return pack8(*(const f32x4*)p, *(const f32x4*)(p + 4));
}
static __device__ inline float exp2_fast(float x) {
#if __has_builtin(__builtin_amdgcn_exp2f)
    return __builtin_amdgcn_exp2f(x);
#else
    return exp2f(x);
#endif
}
// 16B direct global->LDS; lds base wave-uniform, lane i lands at +16*i.
static __device__ inline void gload_lds16(const unsigned short* __restrict__ g,
                                          unsigned short* l, int lane) {
#if __has_builtin(__builtin_amdgcn_global_load_lds)
    __builtin_amdgcn_global_load_lds(
        (const __attribute__((address_space(1))) void*)g,
        (__attribute__((address_space(3))) void*)l, 16, 0, 0);
#else
    *(bf16x8*)((char*)l + lane * 16) = *(const bf16x8*)g;
#endif
}
// V^T k-permutation matching the in-register P fragment of the swapped QK^T:
// within each 32-k block, slot p holds logical k with
//   p = ((k & 12) << 1) | ((k & 16) >> 2) | (k & 3)
static __device__ inline int vperm(int s) {
    return (s & ~31) | ((s & 12) << 1) | ((s & 16) >> 2) | (s & 3);
}

// ---------------------------------------------------------------------------
// f32 -> bf16 bulk convert of x (q,k,v) and W (Wq,Wk,Wv) into ws slabs.
// Lane-coalesced: every f32x4 load and uint2 store is lane-consecutive.
// ---------------------------------------------------------------------------
__global__ __launch_bounds__(256) void cvt_kernel(
    const float* __restrict__ q, const float* __restrict__ k,
    const float* __restrict__ v,
    const float* __restrict__ Wq, const float* __restrict__ Wk,
    const float* __restrict__ Wv,
    unsigned short* __restrict__ xb, unsigned short* __restrict__ wb)
{
    const int by = blockIdx.y;
    const float* src;
    unsigned short* dst;
    size_t base;
    if (blockIdx.x < 1024) {
        src = by == 0 ? q : (by == 1 ? k : v);
        dst = xb + (size_t)by * X_ELEMS;
        base = (size_t)blockIdx.x * 4096;
    } else {
        src = by == 0 ? Wq : (by == 1 ? Wk : Wv);
        dst = wb + (size_t)by * W_ELEMS;
        base = (size_t)(blockIdx.x - 1024) * 4096;
    }
    const int tid = threadIdx.x;
#pragma unroll
    for (int j = 0; j < 4; ++j) {
        const size_t o = base + (size_t)j * 1024 + (size_t)tid * 4;
        const f32x4 a = *(const f32x4*)(src + o);
        u32x2 r;
        r[0] = cvt2(a[0], a[1]);
        r[1] = cvt2(a[2], a[3]);
        *(u32x2*)&dst[o] = r;
    }
}

// ---------------------------------------------------------------------------
// Mask bit-pack: mbits[b][k64][s] = ballot over k-window of 64.
// ---------------------------------------------------------------------------
__global__ __launch_bounds__(256) void pack_mask_kernel(
    const int* __restrict__ mask, unsigned long long* __restrict__ mbits,
    int b_base)
{
    const int w    = blockIdx.x * 4 + (threadIdx.x >> 6);
    const int lane = threadIdx.x & 63;
    const int b    = b_base + (w >> 16);
    const int rem  = w & 65535;
    const int kt   = rem >> 11;
    const int s    = rem & 2047;
    const int v = mask[((size_t)b * S_LEN + s) * S_LEN + kt * 64 + lane];
    const unsigned long long bits = __ballot(v != 0);
    if (lane == 0) mbits[w] = bits;
}

// ---------------------------------------------------------------------------
// proj v2 (m97 structure): bf16 sources, global_load_lds 16B staging.
//   z=0: Q*QSCALE -> d_out f32;  z=1: K -> ws [b][h][s][dh];
//   z=2: V -> ws [b][h][dh][vperm(s)]
// ---------------------------------------------------------------------------
__global__ __launch_bounds__(256) void proj_v2_kernel(
    const unsigned short* __restrict__ xb, const unsigned short* __restrict__ wb,
    const float* __restrict__ bq, const float* __restrict__ bk,
    const float* __restrict__ bv,
    float* __restrict__ q_out, unsigned short* __restrict__ ws)
{
    const int bx = blockIdx.x;
    const int by = blockIdx.y;
    const int z  = by >> 3;
    const int c0 = (by & 7) * 128;

    const unsigned short* A  = xb + (size_t)z * X_ELEMS;
    const unsigned short* Bw = wb + (size_t)z * W_ELEMS;
    const float* bias = z == 0 ? bq : (z == 1 ? bk : bv);

    const int tid  = threadIdx.x;
    const int wave = tid >> 6;
    const int lane = tid & 63;
    const int quad = lane >> 4;
    const int l16  = lane & 15;
    const int m0   = (wave & 1) * 64;
    const int n0   = (wave >> 1) * 64;

    __shared__ __align__(16) unsigned short As[128 * 32];
    __shared__ __align__(16) unsigned short Bs[128 * 32];

    const int r_lo = wave * 16 + (lane >> 2);
    const int r_hi = (wave + 4) * 16 + (lane >> 2);
    const int segu = (lane & 3) * 8;
    const int row0 = bx * 128;

    f32x4 acc[4][4] = {};

    for (int kk = 0; kk < D_MODEL; kk += 32) {
        gload_lds16(A  + (size_t)(row0 + r_lo) * D_MODEL + kk + segu, &As[wave * 512], lane);
        gload_lds16(A  + (size_t)(row0 + r_hi) * D_MODEL + kk + segu, &As[(wave + 4) * 512], lane);
        gload_lds16(Bw + (size_t)(c0 + r_lo) * D_MODEL + kk + segu, &Bs[wave * 512], lane);
        gload_lds16(Bw + (size_t)(c0 + r_hi) * D_MODEL + kk + segu, &Bs[(wave + 4) * 512], lane);
        __syncthreads();

        bf16x8 af[4], bfr[4];
#pragma unroll
        for (int i = 0; i < 4; ++i)
            af[i] = *(const bf16x8*)&As[(m0 + i * 16 + l16) * 32 + quad * 8];
#pragma unroll
        for (int j = 0; j < 4; ++j)
            bfr[j] = *(const bf16x8*)&Bs[(n0 + j * 16 + l16) * 32 + quad * 8];
#pragma unroll
        for (int i = 0; i < 4; ++i)
#pragma unroll
            for (int j = 0; j < 4; ++j)
                acc[i][j] = __builtin_amdgcn_mfma_f32_16x16x32_bf16(
                    af[i], bfr[j], acc[i][j], 0, 0, 0);
        __syncthreads();
    }

#pragma unroll
    for (int j = 0; j < 4; ++j) {
        const int cl  = c0 + n0 + j * 16 + l16;
        const float bval = bias[cl];
        const int h  = cl >> 6;
        const int dh = cl & 63;
#pragma unroll
        for (int i = 0; i < 4; ++i) {
#pragma unroll
            for (int r = 0; r < 4; ++r) {
                const int row = row0 + m0 + i * 16 + quad * 4 + r;
                const float v = acc[i][j][r] + bval;
                if (z == 0) {
                    q_out[(size_t)row * D_MODEL + cl] = v * QSCALE;
                } else {
                    unsigned short* slab = ws + (size_t)(row >> 11) * KVB_WORDS;
                    const int s = row & 2047;
                    if (z == 1)
                        slab[(size_t)h * KV_HSTRIDE + s * DH + dh] = f2bf(v);
                    else
                        slab[WS_V_OFF + (size_t)h * KV_HSTRIDE + dh * S_LEN + vperm(s)] = f2bf(v);
                }
            }
        }
    }
}

// ---------------------------------------------------------------------------
// Fallback proj (f32 staging) for small-ws tiers; same epilogue semantics.
// ---------------------------------------------------------------------------
__global__ __launch_bounds__(256) void proj_fb_kernel(
    const float* __restrict__ q_in, const float* __restrict__ k_in,
    const float* __restrict__ v_in,
    const float* __restrict__ Wq, const float* __restrict__ bq,
    const float* __restrict__ Wk, const float* __restrict__ bk,
    const float* __restrict__ Wv, const float* __restrict__ bv,
    float* __restrict__ q_out, unsigned short* __restrict__ ws, int b_base)
{
    const int bx = blockIdx.x;
    const int by = blockIdx.y;
    const int z  = by >> 3;
    const int c0 = (by & 7) * 128;

    const float* x    = z == 0 ? q_in : (z == 1 ? k_in : v_in);
    const float* W    = z == 0 ? Wq   : (z == 1 ? Wk   : Wv);
    const float* bias = z == 0 ? bq   : (z == 1 ? bk   : bv);

    const int tid  = threadIdx.x;
    const int wave = tid >> 6;
    const int lane = tid & 63;
    const int quad = lane >> 4;
    const int l16  = lane & 15;
    const int m0   = (wave & 1) * 64;
    const int n0   = (wave >> 1) * 64;

    __shared__ __align__(16) unsigned short As[128][40];
    __shared__ __align__(16) unsigned short Bs[128][40];

    const int srow = tid >> 1;
    const int kcol = (tid & 1) * 16;
    const int row0 = b_base * S_LEN + bx * 128;
    const float* ag = x + (size_t)(row0 + srow) * D_MODEL + kcol;
    const float* bg = W + (size_t)(c0 + srow) * D_MODEL + kcol;

    f32x4 acc[4][4] = {};

    for (int kk = 0; kk < D_MODEL; kk += 32) {
        {
            f32x4 a0 = *(const f32x4*)(ag + kk);
            f32x4 a1 = *(const f32x4*)(ag + kk + 4);
            f32x4 a2 = *(const f32x4*)(ag + kk + 8);
            f32x4 a3 = *(const f32x4*)(ag + kk + 12);
            f32x4 b0 = *(const f32x4*)(bg + kk);
            f32x4 b1 = *(const f32x4*)(bg + kk + 4);
            f32x4 b2 = *(const f32x4*)(bg + kk + 8);
            f32x4 b3 = *(const f32x4*)(bg + kk + 12);
            *(bf16x8*)&As[srow][kcol]     = pack8(a0, a1);
            *(bf16x8*)&As[srow][kcol + 8] = pack8(a2, a3);
            *(bf16x8*)&Bs[srow][kcol]     = pack8(b0, b1);
            *(bf16x8*)&Bs[srow][kcol + 8] = pack8(b2, b3);
        }
        __syncthreads();

        bf16x8 af[4], bfr[4];
#pragma unroll
        for (int i = 0; i < 4; ++i)
            af[i] = *(const bf16x8*)&As[m0 + i * 16 + l16][quad * 8];
#pragma unroll
        for (int j = 0; j < 4; ++j)
            bfr[j] = *(const bf16x8*)&Bs[n0 + j * 16 + l16][quad * 8];
#pragma unroll
        for (int i = 0; i < 4; ++i)
#pragma unroll
            for (int j = 0; j < 4; ++j)
                acc[i][j] = __builtin_amdgcn_mfma_f32_16x16x32_bf16(
                    af[i], bfr[j], acc[i][j], 0, 0, 0);
        __syncthreads();
    }

#pragma unroll
    for (int j = 0; j < 4; ++j) {
        const int cl  = c0 + n0 + j * 16 + l16;
        const float bval = bias[cl];
        const int h  = cl >> 6;
        const int dh = cl & 63;
#pragma unroll
        for (int i = 0; i < 4; ++i) {
#pragma unroll
            for (int r = 0; r < 4; ++r) {
                const int row = row0 + m0 + i * 16 + quad * 4 + r;
                const float v = acc[i][j][r] + bval;
                if (z == 0) {
                    q_out[(size_t)row * D_MODEL + cl] = v * QSCALE;
                } else {
                    const int b_rel = (row >> 11) - b_base;
                    const int s     = row & 2047;
                    unsigned short* slab = ws + (size_t)b_rel * KVB_WORDS;
                    if (z == 1)
                        slab[(size_t)h * KV_HSTRIDE + s * DH + dh] = f2bf(v);
                    else
                        slab[WS_V_OFF + (size_t)h * KV_HSTRIDE + dh * S_LEN + vperm(s)] = f2bf(v);
                }
            }
        }
    }
}

// ---------------------------------------------------------------------------
// Flash attention, swapped-QK^T, Q-TILE 128.  K double-buffered in LDS
// (45 KB static, one barrier per K-tile, stage writes after PV).  V is NOT
// staged: PV fragment reads go straight to global -- address audit shows a
// wave's 64 lanes read 16 complete 64B lines per instruction and all 4
// waves read IDENTICAL addresses (L1 broadcast), with the V slab L2/L3-
// resident.  This halves LDS traffic (40 -> 20 ops/iter).  V loads are
// deep-prefetched: d=0,1 issued before QK^T, d=2,3 right after QK^T, both
// consumed ~500+ cycles later.  l-sum = proven VALU+shuffle path.
// ---------------------------------------------------------------------------
__global__ __launch_bounds__(256) void attn_db_kernel(
    const unsigned short* __restrict__ ws,
    const unsigned long long* __restrict__ mbits,
    float* __restrict__ out)
{
    const int h     = blockIdx.x;
    const int qtile = blockIdx.y;
    const int bz    = blockIdx.z;

    const unsigned short* K  = ws + (size_t)bz * KVB_WORDS + (size_t)h * KV_HSTRIDE;
    const unsigned short* Vg = K + WS_V_OFF;
    const unsigned long long* mb = mbits + (size_t)bz * MB_WORDS;

    const int tid  = threadIdx.x;
    const int wave = tid >> 6;
    const int lane = tid & 63;
    const int quad = lane >> 4;
    const int l16  = lane & 15;
    const int q0   = qtile * 128;

    __shared__ __align__(16) unsigned short Kt[2][128 * KSTR];   // 45056 B

    bf16x8 aq0a, aq1a, aq0b, aq1b;
    {
        const float* qa =
            out + (size_t)(bz * S_LEN + q0 + wave * 16 + l16) * D_MODEL + h * DH;
        const float* qb = qa + (size_t)64 * D_MODEL;
        aq0a = cvt8(qa + quad * 8);  aq1a = cvt8(qa + 32 + quad * 8);
        aq0b = cvt8(qb + quad * 8);  aq1b = cvt8(qb + 32 + quad * 8);
    }

    const int qg = q0 + wave * 16 + l16;
    float l_a = 0.f, l_b = 0.f;
    f32x4 o_a[4] = {}, o_b[4] = {};

    const int krow = tid >> 1, kc = (tid & 1) * 32;
    bf16x8 kr[4];
    {
        const unsigned short* kp = K + (size_t)krow * DH + kc;
#pragma unroll
        for (int i = 0; i < 4; ++i) kr[i] = *(const bf16x8*)(kp + 8 * i);
    }
    // Per-lane V^T fragment base: row l16 (+d*16), col quad*8 (+kt*128+c*32).
    const unsigned short* vbase = Vg + (size_t)l16 * S_LEN + quad * 8;

    // mask words for tile 0 (prefetched; rotated each iteration)
    unsigned long long wm0a = mb[qg] >> (quad * 4);
    unsigned long long wm1a = mb[(size_t)S_LEN + qg] >> (quad * 4);
    unsigned long long wm0b = mb[qg + 64] >> (quad * 4);
    unsigned long long wm1b = mb[(size_t)S_LEN + qg + 64] >> (quad * 4);

    // stage K buffer 0
#pragma unroll
    for (int i = 0; i < 4; ++i)
        *(bf16x8*)&Kt[0][krow * KSTR + kc + 8 * i] = kr[i];

    for (int kt = 0; kt < NT; ++kt) {
        __syncthreads();   // K buffer kt&1 fully staged
        const unsigned short* Ktc = Kt[kt & 1];
        const unsigned short* vcol = vbase + kt * KTILE;

        if (kt + 1 < NT) {   // K prefetch for next tile (consumed after PV)
            const unsigned short* kp = K + (size_t)((kt + 1) * KTILE + krow) * DH + kc;
#pragma unroll
            for (int i = 0; i < 4; ++i) kr[i] = *(const bf16x8*)(kp + 8 * i);
        }
        // V fragments d=0,1 — consumed at PV start, ~500+ cycles from here
        bf16x8 vA0[4], vA1[4];
#pragma unroll
        for (int c = 0; c < 4; ++c) {
            vA0[c] = *(const bf16x8*)(vcol + c * 32);
            vA1[c] = *(const bf16x8*)(vcol + (size_t)16 * S_LEN + c * 32);
        }
        unsigned long long nm0a = 0ull, nm1a = 0ull, nm0b = 0ull, nm1b = 0ull;
        if (kt + 1 < NT) {   // prefetch next mask words
            nm0a = mb[(size_t)(2 * kt + 2) * S_LEN + qg] >> (quad * 4);
            nm1a = mb[(size_t)(2 * kt + 3) * S_LEN + qg] >> (quad * 4);
            nm0b = mb[(size_t)(2 * kt + 2) * S_LEN + qg + 64] >> (quad * 4);
            nm1b = mb[(size_t)(2 * kt + 3) * S_LEN + qg + 64] >> (quad * 4);
        }

        // ---- S^T = K Q^T (all 8 blk pairs; col=l16=q, row=blk*16+quad*4+r=k)
        f32x4 sa[8], sb[8];
        __builtin_amdgcn_s_setprio(1);
#pragma unroll
        for (int blk = 0; blk < 8; ++blk) {
            const unsigned short* kb = &Ktc[(blk * 16 + l16) * KSTR];
            bf16x8 k0 = *(const bf16x8*)&kb[quad * 8];
            bf16x8 k1 = *(const bf16x8*)&kb[32 + quad * 8];
            f32x4 z = {0.f, 0.f, 0.f, 0.f};
            sa[blk] = __builtin_amdgcn_mfma_f32_16x16x32_bf16(k0, aq0a, z, 0, 0, 0);
            sa[blk] = __builtin_amdgcn_mfma_f32_16x16x32_bf16(k1, aq1a, sa[blk], 0, 0, 0);
            sb[blk] = __builtin_amdgcn_mfma_f32_16x16x32_bf16(k0, aq0b, z, 0, 0, 0);
            sb[blk] = __builtin_amdgcn_mfma_f32_16x16x32_bf16(k1, aq1b, sb[blk], 0, 0, 0);
        }
        __builtin_amdgcn_s_setprio(0);

        // V fragments d=2,3 — consumed after softmax + PV d0,d1
        bf16x8 vB0[4], vB1[4];
#pragma unroll
        for (int c = 0; c < 4; ++c) {
            vB0[c] = *(const bf16x8*)(vcol + (size_t)32 * S_LEN + c * 32);
            vB1[c] = *(const bf16x8*)(vcol + (size_t)48 * S_LEN + c * 32);
        }

        // ---- p = masked ? 0 : exp2(s); lane-local partial sums ----
#pragma unroll
        for (int blk = 0; blk < 8; ++blk) {
            const unsigned long long wa = (blk < 4) ? wm0a : wm1a;
            const unsigned long long wb = (blk < 4) ? wm0b : wm1b;
            const int sh = (blk & 3) * 16;
#pragma unroll
            for (int r = 0; r < 4; ++r) {
                const bool ma  = (wa >> (sh + r)) & 1ull;
                const bool mbk = (wb >> (sh + r)) & 1ull;
                const float pa = ma  ? 0.0f : exp2_fast(sa[blk][r]);
                const float pb = mbk ? 0.0f : exp2_fast(sb[blk][r]);
                sa[blk][r] = pa; l_a += pa;
                sb[blk][r] = pb; l_b += pb;
            }
        }

        // ---- P -> bf16 A-fragments in-register (k order = vperm) ----
        bf16x8 af_a[4], af_b[4];
#pragma unroll
        for (int c = 0; c < 4; ++c) {
            union { bf16x8 v; unsigned u[4]; } pk;
            pk.u[0] = cvt2(sa[2 * c][0],     sa[2 * c][1]);
            pk.u[1] = cvt2(sa[2 * c][2],     sa[2 * c][3]);
            pk.u[2] = cvt2(sa[2 * c + 1][0], sa[2 * c + 1][1]);
            pk.u[3] = cvt2(sa[2 * c + 1][2], sa[2 * c + 1][3]);
            af_a[c] = pk.v;
            pk.u[0] = cvt2(sb[2 * c][0],     sb[2 * c][1]);
            pk.u[1] = cvt2(sb[2 * c][2],     sb[2 * c][3]);
            pk.u[2] = cvt2(sb[2 * c + 1][0], sb[2 * c + 1][1]);
            pk.u[3] = cvt2(sb[2 * c + 1][2], sb[2 * c + 1][3]);
            af_b[c] = pk.v;
        }

        // ---- PV: V fragments from registers (direct-global) ----
        __builtin_amdgcn_s_setprio(1);
#pragma unroll
        for (int c = 0; c < 4; ++c) {
            o_a[0] = __builtin_amdgcn_mfma_f32_16x16x32_bf16(af_a[c], vA0[c], o_a[0], 0, 0, 0);
            o_b[0] = __builtin_amdgcn_mfma_f32_16x16x32_bf16(af_b[c], vA0[c], o_b[0], 0, 0, 0);
        }
#pragma unroll
        for (int c = 0; c < 4; ++c) {
            o_a[1] = __builtin_amdgcn_mfma_f32_16x16x32_bf16(af_a[c], vA1[c], o_a[1], 0, 0, 0);
            o_b[1] = __builtin_amdgcn_mfma_f32_16x16x32_bf16(af_b[c], vA1[c], o_b[1], 0, 0, 0);
        }
#pragma unroll
        for (int c = 0; c < 4; ++c) {
            o_a[2] = __builtin_amdgcn_mfma_f32_16x16x32_bf16(af_a[c], vB0[c], o_a[2], 0, 0, 0);
            o_b[2] = __builtin_amdgcn_mfma_f32_16x16x32_bf16(af_b[c], vB0[c], o_b[2], 0, 0, 0);
        }
#pragma unroll
        for (int c = 0; c < 4; ++c) {
            o_a[3] = __builtin_amdgcn_mfma_f32_16x16x32_bf16(af_a[c], vB1[c], o_a[3], 0, 0, 0);
            o_b[3] = __builtin_amdgcn_mfma_f32_16x16x32_bf16(af_b[c], vB1[c], o_b[3], 0, 0, 0);
        }
        __builtin_amdgcn_s_setprio(0);

        if (kt + 1 < NT) {   // write-late K stage into the other buffer
#pragma unroll
            for (int i = 0; i < 4; ++i)
                *(bf16x8*)&Kt[(kt + 1) & 1][krow * KSTR + kc + 8 * i] = kr[i];
        }
        wm0a = nm0a; wm1a = nm1a; wm0b = nm0b; wm1b = nm1b;
    }

    // l-reduce: sum the 4 quad partials of each q row, then broadcast.
    l_a += __shfl_xor(l_a, 16, 64);
    l_a += __shfl_xor(l_a, 32, 64);
    l_b += __shfl_xor(l_b, 16, 64);
    l_b += __shfl_xor(l_b, 32, 64);

#pragma unroll
    for (int r = 0; r < 4; ++r) {
        const float la = __shfl(l_a, quad * 4 + r, 64);
        const float lb = __shfl(l_b, quad * 4 + r, 64);
        const float ia = 1.0f / fmaxf(la, 1e-30f);
        const float ib = 1.0f / fmaxf(lb, 1e-30f);
        const int qgr = q0 + wave * 16 + quad * 4 + r;
#pragma unroll
        for (int d = 0; d < 4; ++d) {
            out[((size_t)(bz * S_LEN) + qgr) * D_MODEL + h * DH + d * 16 + l16] =
                o_a[d][r] * ia;
            out[((size_t)(bz * S_LEN) + qgr + 64) * D_MODEL + h * DH + d * 16 + l16] =
                o_b[d][r] * ib;
        }
    }
}

// ---------------------------------------------------------------------------
// Single-buffer attention (round-4 measured version) — small-ws fallback.
// ---------------------------------------------------------------------------
__global__ __launch_bounds__(256) void attn_sb_kernel(
    const unsigned short* __restrict__ ws,
    const unsigned long long* __restrict__ mbits,
    const int* __restrict__ mask,
    float* __restrict__ out, int b_base, int use_bits)
{
    const int h     = blockIdx.x;
    const int qtile = blockIdx.y;
    const int bz    = blockIdx.z;
    const int b0    = b_base + bz;

    const unsigned short* K  = ws + (size_t)bz * KVB_WORDS + (size_t)h * KV_HSTRIDE;
    const unsigned short* Vg = K + WS_V_OFF;
    const unsigned long long* mb = mbits + (size_t)bz * MB_WORDS;

    const int tid  = threadIdx.x;
    const int wave = tid >> 6;
    const int lane = tid & 63;
    const int quad = lane >> 4;
    const int l16  = lane & 15;
    const int q0   = qtile * 128;

    __shared__ __align__(16) unsigned short Vt[64][VSTR];
    __shared__ __align__(16) unsigned short Kt[128 * KSTR];

    bf16x8 aq0a, aq1a, aq0b, aq1b;
    {
        const float* qa =
            out + (size_t)(b0 * S_LEN + q0 + wave * 16 + l16) * D_MODEL + h * DH;
        const float* qb = qa + (size_t)64 * D_MODEL;
        aq0a = cvt8(qa + quad * 8);  aq1a = cvt8(qa + 32 + quad * 8);
        aq0b = cvt8(qb + quad * 8);  aq1b = cvt8(qb + 32 + quad * 8);
    }

    const int qg = q0 + wave * 16 + l16;
    float l_a = 0.f, l_b = 0.f;
    f32x4 o_a[4] = {}, o_b[4] = {};

    const int krow = tid >> 1, kc = (tid & 1) * 32;
    const int vrow = tid >> 2, vc = (tid & 3) * 32;
    bf16x8 kr[4], vr[4];
    {
        const unsigned short* kp = K + (size_t)krow * DH + kc;
        const unsigned short* vp = Vg + (size_t)vrow * S_LEN + vc;
#pragma unroll
        for (int i = 0; i < 4; ++i) {
            kr[i] = *(const bf16x8*)(kp + 8 * i);
            vr[i] = *(const bf16x8*)(vp + 8 * i);
        }
    }

    for (int kt = 0; kt < NT; ++kt) {
#pragma unroll
        for (int i = 0; i < 4; ++i) {
            *(bf16x8*)&Kt[krow * KSTR + kc + 8 * i] = kr[i];
            *(bf16x8*)&Vt[vrow][vc + 8 * i]         = vr[i];
        }
        __syncthreads();

        if (kt + 1 < NT) {
            const unsigned short* kp = K + (size_t)((kt + 1) * KTILE + krow) * DH + kc;
            const unsigned short* vp = Vg + (size_t)vrow * S_LEN + (kt + 1) * KTILE + vc;
#pragma unroll
            for (int i = 0; i < 4; ++i) {
                kr[i] = *(const bf16x8*)(kp + 8 * i);
                vr[i] = *(const bf16x8*)(vp + 8 * i);
            }
        }

        unsigned long long wm0a = 0ull, wm1a = 0ull, wm0b = 0ull, wm1b = 0ull;
        if (use_bits) {
            wm0a = mb[(size_t)(2 * kt) * S_LEN + qg] >> (quad * 4);
            wm1a = mb[(size_t)(2 * kt + 1) * S_LEN + qg] >> (quad * 4);
            wm0b = mb[(size_t)(2 * kt) * S_LEN + qg + 64] >> (quad * 4);
            wm1b = mb[(size_t)(2 * kt + 1) * S_LEN + qg + 64] >> (quad * 4);
        }

        bf16x8 af_a[4], af_b[4];
#pragma unroll
        for (int c = 0; c < 4; ++c) {
            f32x4 sa[2], sb[2];
#pragma unroll
            for (int j = 0; j < 2; ++j) {
                const int blk = 2 * c + j;
                const unsigned short* kb = &Kt[(blk * 16 + l16) * KSTR];
                bf16x8 k0 = *(const bf16x8*)&kb[quad * 8];
                bf16x8 k1 = *(const bf16x8*)&kb[32 + quad * 8];
                f32x4 z = {0.f, 0.f, 0.f, 0.f};
                sa[j] = __builtin_amdgcn_mfma_f32_16x16x32_bf16(k0, aq0a, z, 0, 0, 0);
                sa[j] = __builtin_amdgcn_mfma_f32_16x16x32_bf16(k1, aq1a, sa[j], 0, 0, 0);
                sb[j] = __builtin_amdgcn_mfma_f32_16x16x32_bf16(k0, aq0b, z, 0, 0, 0);
                sb[j] = __builtin_amdgcn_mfma_f32_16x16x32_bf16(k1, aq1b, sb[j], 0, 0, 0);
            }
#pragma unroll
            for (int j = 0; j < 2; ++j) {
                const int blk = 2 * c + j;
                const unsigned long long wa = (blk < 4) ? wm0a : wm1a;
                const unsigned long long wb = (blk < 4) ? wm0b : wm1b;
                const int sh = (blk & 3) * 16;
#pragma unroll
                for (int r = 0; r < 4; ++r) {
                    bool ma, mbk;
                    if (use_bits) {
                        ma  = (wa >> (sh + r)) & 1ull;
                        mbk = (wb >> (sh + r)) & 1ull;
                    } else {
                        const int kg = kt * KTILE + blk * 16 + quad * 4 + r;
                        ma  = mask[((size_t)(b0 * S_LEN) + qg) * S_LEN + kg] != 0;
                        mbk = mask[((size_t)(b0 * S_LEN) + qg + 64) * S_LEN + kg] != 0;
                    }
                    const float pa = ma  ? 0.0f : exp2_fast(sa[j][r]);
                    const float pb = mbk ? 0.0f : exp2_fast(sb[j][r]);
                    sa[j][r] = pa; l_a += pa;
                    sb[j][r] = pb; l_b += pb;
                }
            }
            {
                union { bf16x8 v; unsigned u[4]; } pk;
                pk.u[0] = cvt2(sa[0][0], sa[0][1]);
                pk.u[1] = cvt2(sa[0][2], sa[0][3]);
                pk.u[2] = cvt2(sa[1][0], sa[1][1]);
                pk.u[3] = cvt2(sa[1][2], sa[1][3]);
                af_a[c] = pk.v;
                pk.u[0] = cvt2(sb[0][0], sb[0][1]);
                pk.u[1] = cvt2(sb[0][2], sb[0][3]);
                pk.u[2] = cvt2(sb[1][0], sb[1][1]);
                pk.u[3] = cvt2(sb[1][2], sb[1][3]);
                af_b[c] = pk.v;
            }
        }

#pragma unroll
        for (int d = 0; d < 4; ++d) {
#pragma unroll
            for (int c = 0; c < 4; ++c) {
                bf16x8 bv = *(const bf16x8*)&Vt[d * 16 + l16][c * 32 + quad * 8];
                o_a[d] = __builtin_amdgcn_mfma_f32_16x16x32_bf16(af_a[c], bv, o_a[d], 0, 0, 0);
                o_b[d] = __builtin_amdgcn_mfma_f32_16x16x32_bf16(af_b[c], bv, o_b[d], 0, 0, 0);
            }
        }
        __syncthreads();
    }

    l_a += __shfl_xor(l_a, 16, 64);
    l_a += __shfl_xor(l_a, 32, 64);
    l_b += __shfl_xor(l_b, 16, 64);
    l_b += __shfl_xor(l_b, 32, 64);

#pragma unroll
    for (int r = 0; r < 4; ++r) {
        const float la = __shfl(l_a, quad * 4 + r, 64);
        const float lb = __shfl(l_b, quad * 4 + r, 64);
        const float ia = 1.0f / fmaxf(la, 1e-30f);
        const float ib = 1.0f / fmaxf(lb, 1e-30f);
        const int qgr = q0 + wave * 16 + quad * 4 + r;
#pragma unroll
        for (int d = 0; d < 4; ++d) {
            out[((size_t)(b0 * S_LEN) + qgr) * D_MODEL + h * DH + d * 16 + l16] =
                o_a[d][r] * ia;
            out[((size_t)(b0 * S_LEN) + qgr + 64) * D_MODEL + h * DH + d * 16 + l16] =
                o_b[d][r] * ib;
        }
    }
}

extern "C" void kernel_launch(void* const* d_in, const int* in_sizes, int n_in,
                              void* d_out, int out_size, void* d_ws, size_t ws_size,
                              hipStream_t stream) {
    const float* query = (const float*)d_in[0];
    const float* key   = (const float*)d_in[1];
    const float* value = (const float*)d_in[2];
    const int*   mask  = (const int*)d_in[3];
    const float* Wq    = (const float*)d_in[4];
    const float* bq    = (const float*)d_in[5];
    const float* Wk    = (const float*)d_in[6];
    const float* bk    = (const float*)d_in[7];
    const float* Wv    = (const float*)d_in[8];
    const float* bv    = (const float*)d_in[9];

    unsigned short* ws   = (unsigned short*)d_ws;
    float*          outp = (float*)d_out;

    const size_t KV_BYTES = (size_t)KVB_WORDS * 2;
    const size_t MB_BYTES = (size_t)MB_WORDS * 8;
    const size_t XB_BYTES = (size_t)3 * X_ELEMS * 2;
    const size_t WB_BYTES = (size_t)3 * W_ELEMS * 2;
    const size_t base2    = 2 * KV_BYTES + 2 * MB_BYTES;

    if (ws_size >= base2 + XB_BYTES + WB_BYTES) {
        unsigned long long* mbits = (unsigned long long*)(ws + 2 * KVB_WORDS);
        unsigned short* xb = ws + base2 / 2;
        unsigned short* wb = xb + (size_t)3 * X_ELEMS;
        cvt_kernel<<<dim3(1280, 3), 256, 0, stream>>>(
            query, key, value, Wq, Wk, Wv, xb, wb);
        proj_v2_kernel<<<dim3(32, 24), 256, 0, stream>>>(
            xb, wb, bq, bk, bv, outp, ws);
        pack_mask_kernel<<<dim3(2 * MB_WORDS / 4), 256, 0, stream>>>(mask, mbits, 0);
        attn_db_kernel<<<dim3(NH, S_LEN / 128, 2), 256, 0, stream>>>(
            ws, mbits, outp);
    } else if (ws_size >= base2) {
        unsigned long long* mbits = (unsigned long long*)(ws + 2 * KVB_WORDS);
        proj_fb_kernel<<<dim3(32, 24), 256, 0, stream>>>(
            query, key, value, Wq, bq, Wk, bk, Wv, bv, outp, ws, 0);
        pack_mask_kernel<<<dim3(2 * MB_WORDS / 4), 256, 0, stream>>>(mask, mbits, 0);
        attn_db_kernel<<<dim3(NH, S_LEN / 128, 2), 256, 0, stream>>>(
            ws, mbits, outp);
    } else if (ws_size >= KV_BYTES + MB_BYTES) {
        unsigned long long* mbits = (unsigned long long*)(ws + KVB_WORDS);
        for (int b0 = 0; b0 < BATCH; ++b0) {
            proj_fb_kernel<<<dim3(16, 24), 256, 0, stream>>>(
                query, key, value, Wq, bq, Wk, bk, Wv, bv, outp, ws, b0);
            pack_mask_kernel<<<dim3(MB_WORDS / 4), 256, 0, stream>>>(mask, mbits, b0);
            attn_sb_kernel<<<dim3(NH, S_LEN / 128, 1), 256, 0, stream>>>(
                ws, mbits, mask, outp, b0, 1);
        }
    } else {
        for (int b0 = 0; b0 < BATCH; ++b0) {
            proj_fb_kernel<<<dim3(16, 24), 256, 0, stream>>>(
                query, key, value, Wq, bq, Wk, bk, Wv, bv, outp, ws, b0);
            attn_sb_kernel<<<dim3(NH, S_LEN / 128, 1), 256, 0, stream>>>(
                ws, (const unsigned long long*)ws, mask, outp, b0, 0);
        }
    }
}

// Round 8
// 251.770 us; speedup vs baseline: 1.1846x; 1.1846x over previous
//
#include <hip/hip_runtime.h>
#include <hip/hip_bf16.h>

#define D_MODEL 1024
#define NH 16
#define DH 64
#define S_LEN 2048
#define BATCH 2
// Q folded scale: 1/sqrt(64) * log2(e) so softmax uses exp2 with m == 0.
#define QSCALE (0.125f * 1.44269504088896f)

#define KV_HSTRIDE (S_LEN * DH)           // ushorts per head slab
#define WS_V_OFF   (NH * KV_HSTRIDE)      // V^T offset within a batch slab
#define KVB_WORDS  (2 * NH * KV_HSTRIDE)  // ushorts per batch K+V slab (8.39 MB)
#define MB_WORDS   ((S_LEN / 64) * S_LEN) // uint64 mask words per batch (512 KB)
#define KTILE 128
#define NT (S_LEN / KTILE)
#define X_ELEMS (BATCH * S_LEN * D_MODEL)   // 4.19M per tensor
#define W_ELEMS (D_MODEL * D_MODEL)         // 1.05M per tensor
#define KSTR 88                             // Kt row stride (176 B, 16B-aligned)
#define VSTR 136                            // Vt row stride (272 B, 16B-aligned)
#define BUFW (128 * KSTR + 64 * VSTR)       // ushorts per K+V LDS buffer (39936 B)
#define BUF_BYTES (BUFW * 2)

typedef __attribute__((ext_vector_type(8))) short bf16x8;
typedef __attribute__((ext_vector_type(4))) float f32x4;
typedef __attribute__((ext_vector_type(2))) unsigned int u32x2;

static __device__ inline unsigned short f2bf(float f) {
    union { float f; unsigned u; } v; v.f = f;
    unsigned r = v.u + 0x7fffu + ((v.u >> 16) & 1u);
    return (unsigned short)(r >> 16);
}
static __device__ inline unsigned cvt2(float a, float b) {
    union { __hip_bfloat162 h2; unsigned u; } cv;
    cv.h2 = __float22bfloat162_rn(make_float2(a, b));
    return cv.u;
}
static __device__ inline bf16x8 pack8(f32x4 a, f32x4 b) {
    union { bf16x8 v; unsigned u[4]; } r;
    r.u[0] = cvt2(a[0], a[1]); r.u[1] = cvt2(a[2], a[3]);
    r.u[2] = cvt2(b[0], b[1]); r.u[3] = cvt2(b[2], b[3]);
    return r.v;
}
static __device__ inline bf16x8 cvt8(const float* __restrict__ p) {
    return pack8(*(const f32x4*)p, *(const f32x4*)(p + 4));
}
static __device__ inline float exp2_fast(float x) {
#if __has_builtin(__builtin_amdgcn_exp2f)
    return __builtin_amdgcn_exp2f(x);
#else
    return exp2f(x);
#endif
}
// 16B direct global->LDS; lds base wave-uniform, lane i lands at +16*i.
static __device__ inline void gload_lds16(const unsigned short* __restrict__ g,
                                          unsigned short* l, int lane) {
#if __has_builtin(__builtin_amdgcn_global_load_lds)
    __builtin_amdgcn_global_load_lds(
        (const __attribute__((address_space(1))) void*)g,
        (__attribute__((address_space(3))) void*)l, 16, 0, 0);
#else
    *(bf16x8*)((char*)l + lane * 16) = *(const bf16x8*)g;
#endif
}
// V^T k-permutation matching the in-register P fragment of the swapped QK^T:
// within each 32-k block, slot p holds logical k with
//   p = ((k & 12) << 1) | ((k & 16) >> 2) | (k & 3)
static __device__ inline int vperm(int s) {
    return (s & ~31) | ((s & 12) << 1) | ((s & 16) >> 2) | (s & 3);
}

// ---------------------------------------------------------------------------
// f32 -> bf16 bulk convert of x (q,k,v) and W (Wq,Wk,Wv) into ws slabs.
// Lane-coalesced: every f32x4 load and uint2 store is lane-consecutive
// (adjacent lanes 16 B / 8 B apart) — proven −9 µs vs per-thread-contiguous.
// ---------------------------------------------------------------------------
__global__ __launch_bounds__(256) void cvt_kernel(
    const float* __restrict__ q, const float* __restrict__ k,
    const float* __restrict__ v,
    const float* __restrict__ Wq, const float* __restrict__ Wk,
    const float* __restrict__ Wv,
    unsigned short* __restrict__ xb, unsigned short* __restrict__ wb)
{
    const int by = blockIdx.y;
    const float* src;
    unsigned short* dst;
    size_t base;
    if (blockIdx.x < 1024) {
        src = by == 0 ? q : (by == 1 ? k : v);
        dst = xb + (size_t)by * X_ELEMS;
        base = (size_t)blockIdx.x * 4096;
    } else {
        src = by == 0 ? Wq : (by == 1 ? Wk : Wv);
        dst = wb + (size_t)by * W_ELEMS;
        base = (size_t)(blockIdx.x - 1024) * 4096;
    }
    const int tid = threadIdx.x;
#pragma unroll
    for (int j = 0; j < 4; ++j) {
        const size_t o = base + (size_t)j * 1024 + (size_t)tid * 4;
        const f32x4 a = *(const f32x4*)(src + o);
        u32x2 r;
        r[0] = cvt2(a[0], a[1]);
        r[1] = cvt2(a[2], a[3]);
        *(u32x2*)&dst[o] = r;
    }
}

// ---------------------------------------------------------------------------
// Mask bit-pack: mbits[b][k64][s] = ballot over k-window of 64.
// ---------------------------------------------------------------------------
__global__ __launch_bounds__(256) void pack_mask_kernel(
    const int* __restrict__ mask, unsigned long long* __restrict__ mbits,
    int b_base)
{
    const int w    = blockIdx.x * 4 + (threadIdx.x >> 6);
    const int lane = threadIdx.x & 63;
    const int b    = b_base + (w >> 16);
    const int rem  = w & 65535;
    const int kt   = rem >> 11;
    const int s    = rem & 2047;
    const int v = mask[((size_t)b * S_LEN + s) * S_LEN + kt * 64 + lane];
    const unsigned long long bits = __ballot(v != 0);
    if (lane == 0) mbits[w] = bits;
}

// ---------------------------------------------------------------------------
// proj v2 (m97 structure): bf16 sources, global_load_lds 16B staging.
//   z=0: Q*QSCALE -> d_out f32;  z=1: K -> ws [b][h][s][dh];
//   z=2: V -> ws [b][h][dh][vperm(s)]
// ---------------------------------------------------------------------------
__global__ __launch_bounds__(256) void proj_v2_kernel(
    const unsigned short* __restrict__ xb, const unsigned short* __restrict__ wb,
    const float* __restrict__ bq, const float* __restrict__ bk,
    const float* __restrict__ bv,
    float* __restrict__ q_out, unsigned short* __restrict__ ws)
{
    const int bx = blockIdx.x;
    const int by = blockIdx.y;
    const int z  = by >> 3;
    const int c0 = (by & 7) * 128;

    const unsigned short* A  = xb + (size_t)z * X_ELEMS;
    const unsigned short* Bw = wb + (size_t)z * W_ELEMS;
    const float* bias = z == 0 ? bq : (z == 1 ? bk : bv);

    const int tid  = threadIdx.x;
    const int wave = tid >> 6;
    const int lane = tid & 63;
    const int quad = lane >> 4;
    const int l16  = lane & 15;
    const int m0   = (wave & 1) * 64;
    const int n0   = (wave >> 1) * 64;

    __shared__ __align__(16) unsigned short As[128 * 32];
    __shared__ __align__(16) unsigned short Bs[128 * 32];

    const int r_lo = wave * 16 + (lane >> 2);
    const int r_hi = (wave + 4) * 16 + (lane >> 2);
    const int segu = (lane & 3) * 8;
    const int row0 = bx * 128;

    f32x4 acc[4][4] = {};

    for (int kk = 0; kk < D_MODEL; kk += 32) {
        gload_lds16(A  + (size_t)(row0 + r_lo) * D_MODEL + kk + segu, &As[wave * 512], lane);
        gload_lds16(A  + (size_t)(row0 + r_hi) * D_MODEL + kk + segu, &As[(wave + 4) * 512], lane);
        gload_lds16(Bw + (size_t)(c0 + r_lo) * D_MODEL + kk + segu, &Bs[wave * 512], lane);
        gload_lds16(Bw + (size_t)(c0 + r_hi) * D_MODEL + kk + segu, &Bs[(wave + 4) * 512], lane);
        __syncthreads();

        bf16x8 af[4], bfr[4];
#pragma unroll
        for (int i = 0; i < 4; ++i)
            af[i] = *(const bf16x8*)&As[(m0 + i * 16 + l16) * 32 + quad * 8];
#pragma unroll
        for (int j = 0; j < 4; ++j)
            bfr[j] = *(const bf16x8*)&Bs[(n0 + j * 16 + l16) * 32 + quad * 8];
#pragma unroll
        for (int i = 0; i < 4; ++i)
#pragma unroll
            for (int j = 0; j < 4; ++j)
                acc[i][j] = __builtin_amdgcn_mfma_f32_16x16x32_bf16(
                    af[i], bfr[j], acc[i][j], 0, 0, 0);
        __syncthreads();
    }

#pragma unroll
    for (int j = 0; j < 4; ++j) {
        const int cl  = c0 + n0 + j * 16 + l16;
        const float bval = bias[cl];
        const int h  = cl >> 6;
        const int dh = cl & 63;
#pragma unroll
        for (int i = 0; i < 4; ++i) {
#pragma unroll
            for (int r = 0; r < 4; ++r) {
                const int row = row0 + m0 + i * 16 + quad * 4 + r;
                const float v = acc[i][j][r] + bval;
                if (z == 0) {
                    q_out[(size_t)row * D_MODEL + cl] = v * QSCALE;
                } else {
                    unsigned short* slab = ws + (size_t)(row >> 11) * KVB_WORDS;
                    const int s = row & 2047;
                    if (z == 1)
                        slab[(size_t)h * KV_HSTRIDE + s * DH + dh] = f2bf(v);
                    else
                        slab[WS_V_OFF + (size_t)h * KV_HSTRIDE + dh * S_LEN + vperm(s)] = f2bf(v);
                }
            }
        }
    }
}

// ---------------------------------------------------------------------------
// Fallback proj (f32 staging) for small-ws tiers; same epilogue semantics.
// ---------------------------------------------------------------------------
__global__ __launch_bounds__(256) void proj_fb_kernel(
    const float* __restrict__ q_in, const float* __restrict__ k_in,
    const float* __restrict__ v_in,
    const float* __restrict__ Wq, const float* __restrict__ bq,
    const float* __restrict__ Wk, const float* __restrict__ bk,
    const float* __restrict__ Wv, const float* __restrict__ bv,
    float* __restrict__ q_out, unsigned short* __restrict__ ws, int b_base)
{
    const int bx = blockIdx.x;
    const int by = blockIdx.y;
    const int z  = by >> 3;
    const int c0 = (by & 7) * 128;

    const float* x    = z == 0 ? q_in : (z == 1 ? k_in : v_in);
    const float* W    = z == 0 ? Wq   : (z == 1 ? Wk   : Wv);
    const float* bias = z == 0 ? bq   : (z == 1 ? bk   : bv);

    const int tid  = threadIdx.x;
    const int wave = tid >> 6;
    const int lane = tid & 63;
    const int quad = lane >> 4;
    const int l16  = lane & 15;
    const int m0   = (wave & 1) * 64;
    const int n0   = (wave >> 1) * 64;

    __shared__ __align__(16) unsigned short As[128][40];
    __shared__ __align__(16) unsigned short Bs[128][40];

    const int srow = tid >> 1;
    const int kcol = (tid & 1) * 16;
    const int row0 = b_base * S_LEN + bx * 128;
    const float* ag = x + (size_t)(row0 + srow) * D_MODEL + kcol;
    const float* bg = W + (size_t)(c0 + srow) * D_MODEL + kcol;

    f32x4 acc[4][4] = {};

    for (int kk = 0; kk < D_MODEL; kk += 32) {
        {
            f32x4 a0 = *(const f32x4*)(ag + kk);
            f32x4 a1 = *(const f32x4*)(ag + kk + 4);
            f32x4 a2 = *(const f32x4*)(ag + kk + 8);
            f32x4 a3 = *(const f32x4*)(ag + kk + 12);
            f32x4 b0 = *(const f32x4*)(bg + kk);
            f32x4 b1 = *(const f32x4*)(bg + kk + 4);
            f32x4 b2 = *(const f32x4*)(bg + kk + 8);
            f32x4 b3 = *(const f32x4*)(bg + kk + 12);
            *(bf16x8*)&As[srow][kcol]     = pack8(a0, a1);
            *(bf16x8*)&As[srow][kcol + 8] = pack8(a2, a3);
            *(bf16x8*)&Bs[srow][kcol]     = pack8(b0, b1);
            *(bf16x8*)&Bs[srow][kcol + 8] = pack8(b2, b3);
        }
        __syncthreads();

        bf16x8 af[4], bfr[4];
#pragma unroll
        for (int i = 0; i < 4; ++i)
            af[i] = *(const bf16x8*)&As[m0 + i * 16 + l16][quad * 8];
#pragma unroll
        for (int j = 0; j < 4; ++j)
            bfr[j] = *(const bf16x8*)&Bs[n0 + j * 16 + l16][quad * 8];
#pragma unroll
        for (int i = 0; i < 4; ++i)
#pragma unroll
            for (int j = 0; j < 4; ++j)
                acc[i][j] = __builtin_amdgcn_mfma_f32_16x16x32_bf16(
                    af[i], bfr[j], acc[i][j], 0, 0, 0);
        __syncthreads();
    }

#pragma unroll
    for (int j = 0; j < 4; ++j) {
        const int cl  = c0 + n0 + j * 16 + l16;
        const float bval = bias[cl];
        const int h  = cl >> 6;
        const int dh = cl & 63;
#pragma unroll
        for (int i = 0; i < 4; ++i) {
#pragma unroll
            for (int r = 0; r < 4; ++r) {
                const int row = row0 + m0 + i * 16 + quad * 4 + r;
                const float v = acc[i][j][r] + bval;
                if (z == 0) {
                    q_out[(size_t)row * D_MODEL + cl] = v * QSCALE;
                } else {
                    const int b_rel = (row >> 11) - b_base;
                    const int s     = row & 2047;
                    unsigned short* slab = ws + (size_t)b_rel * KVB_WORDS;
                    if (z == 1)
                        slab[(size_t)h * KV_HSTRIDE + s * DH + dh] = f2bf(v);
                    else
                        slab[WS_V_OFF + (size_t)h * KV_HSTRIDE + dh * S_LEN + vperm(s)] = f2bf(v);
                }
            }
        }
    }
}

// ---------------------------------------------------------------------------
// Flash attention, swapped-QK^T, Q-TILE 128, DOUBLE-BUFFERED LDS (dynamic,
// 79.9 KB/block, 2 blocks/CU).  One barrier per K-tile; stage writes land
// after PV; setprio(1) wraps MFMA clusters; mask words prefetched one iter
// ahead; l-sum via lane-local adds + epilogue shuffles (proven fastest).
// This is the round-5 measured configuration (73.7 us) verbatim.
// ---------------------------------------------------------------------------
__global__ __launch_bounds__(256) void attn_db_kernel(
    const unsigned short* __restrict__ ws,
    const unsigned long long* __restrict__ mbits,
    float* __restrict__ out)
{
    const int h     = blockIdx.x;
    const int qtile = blockIdx.y;
    const int bz    = blockIdx.z;

    const unsigned short* K  = ws + (size_t)bz * KVB_WORDS + (size_t)h * KV_HSTRIDE;
    const unsigned short* Vg = K + WS_V_OFF;
    const unsigned long long* mb = mbits + (size_t)bz * MB_WORDS;

    const int tid  = threadIdx.x;
    const int wave = tid >> 6;
    const int lane = tid & 63;
    const int quad = lane >> 4;
    const int l16  = lane & 15;
    const int q0   = qtile * 128;

    extern __shared__ __align__(16) unsigned short lds[];

    bf16x8 aq0a, aq1a, aq0b, aq1b;
    {
        const float* qa =
            out + (size_t)(bz * S_LEN + q0 + wave * 16 + l16) * D_MODEL + h * DH;
        const float* qb = qa + (size_t)64 * D_MODEL;
        aq0a = cvt8(qa + quad * 8);  aq1a = cvt8(qa + 32 + quad * 8);
        aq0b = cvt8(qb + quad * 8);  aq1b = cvt8(qb + 32 + quad * 8);
    }

    const int qg = q0 + wave * 16 + l16;
    float l_a = 0.f, l_b = 0.f;
    f32x4 o_a[4] = {}, o_b[4] = {};

    const int krow = tid >> 1, kc = (tid & 1) * 32;
    const int vrow = tid >> 2, vc = (tid & 3) * 32;
    bf16x8 kr[4], vr[4];
    {
        const unsigned short* kp = K + (size_t)krow * DH + kc;
        const unsigned short* vp = Vg + (size_t)vrow * S_LEN + vc;
#pragma unroll
        for (int i = 0; i < 4; ++i) {
            kr[i] = *(const bf16x8*)(kp + 8 * i);
            vr[i] = *(const bf16x8*)(vp + 8 * i);
        }
    }
    // mask words for tile 0 (prefetched; rotated each iteration)
    unsigned long long wm0a = mb[qg] >> (quad * 4);
    unsigned long long wm1a = mb[(size_t)S_LEN + qg] >> (quad * 4);
    unsigned long long wm0b = mb[qg + 64] >> (quad * 4);
    unsigned long long wm1b = mb[(size_t)S_LEN + qg + 64] >> (quad * 4);

    // stage buffer 0
    {
        unsigned short* Kt0 = lds;
        unsigned short* Vt0 = lds + 128 * KSTR;
#pragma unroll
        for (int i = 0; i < 4; ++i) {
            *(bf16x8*)&Kt0[krow * KSTR + kc + 8 * i] = kr[i];
            *(bf16x8*)&Vt0[vrow * VSTR + vc + 8 * i] = vr[i];
        }
    }

    for (int kt = 0; kt < NT; ++kt) {
        __syncthreads();   // buffer kt&1 fully staged
        unsigned short* Ktc = lds + (kt & 1) * BUFW;
        unsigned short* Vtc = Ktc + 128 * KSTR;

        if (kt + 1 < NT) {   // issue next-tile global loads early (write-late)
            const unsigned short* kp = K + (size_t)((kt + 1) * KTILE + krow) * DH + kc;
            const unsigned short* vp = Vg + (size_t)vrow * S_LEN + (kt + 1) * KTILE + vc;
#pragma unroll
            for (int i = 0; i < 4; ++i) {
                kr[i] = *(const bf16x8*)(kp + 8 * i);
                vr[i] = *(const bf16x8*)(vp + 8 * i);
            }
        }
        unsigned long long nm0a = 0ull, nm1a = 0ull, nm0b = 0ull, nm1b = 0ull;
        if (kt + 1 < NT) {   // prefetch next mask words
            nm0a = mb[(size_t)(2 * kt + 2) * S_LEN + qg] >> (quad * 4);
            nm1a = mb[(size_t)(2 * kt + 3) * S_LEN + qg] >> (quad * 4);
            nm0b = mb[(size_t)(2 * kt + 2) * S_LEN + qg + 64] >> (quad * 4);
            nm1b = mb[(size_t)(2 * kt + 3) * S_LEN + qg + 64] >> (quad * 4);
        }

        // ---- S^T = K Q^T + softmax + pack, fused per blk-pair (c) ----
        bf16x8 af_a[4], af_b[4];
#pragma unroll
        for (int c = 0; c < 4; ++c) {
            f32x4 sa[2], sb[2];
            __builtin_amdgcn_s_setprio(1);
#pragma unroll
            for (int j = 0; j < 2; ++j) {
                const int blk = 2 * c + j;
                const unsigned short* kb = &Ktc[(blk * 16 + l16) * KSTR];
                bf16x8 k0 = *(const bf16x8*)&kb[quad * 8];
                bf16x8 k1 = *(const bf16x8*)&kb[32 + quad * 8];
                f32x4 z = {0.f, 0.f, 0.f, 0.f};
                sa[j] = __builtin_amdgcn_mfma_f32_16x16x32_bf16(k0, aq0a, z, 0, 0, 0);
                sa[j] = __builtin_amdgcn_mfma_f32_16x16x32_bf16(k1, aq1a, sa[j], 0, 0, 0);
                sb[j] = __builtin_amdgcn_mfma_f32_16x16x32_bf16(k0, aq0b, z, 0, 0, 0);
                sb[j] = __builtin_amdgcn_mfma_f32_16x16x32_bf16(k1, aq1b, sb[j], 0, 0, 0);
            }
            __builtin_amdgcn_s_setprio(0);
#pragma unroll
            for (int j = 0; j < 2; ++j) {
                const int blk = 2 * c + j;
                const unsigned long long wa = (blk < 4) ? wm0a : wm1a;
                const unsigned long long wb = (blk < 4) ? wm0b : wm1b;
                const int sh = (blk & 3) * 16;
#pragma unroll
                for (int r = 0; r < 4; ++r) {
                    const bool ma  = (wa >> (sh + r)) & 1ull;
                    const bool mbk = (wb >> (sh + r)) & 1ull;
                    const float pa = ma  ? 0.0f : exp2_fast(sa[j][r]);
                    const float pb = mbk ? 0.0f : exp2_fast(sb[j][r]);
                    sa[j][r] = pa; l_a += pa;
                    sb[j][r] = pb; l_b += pb;
                }
            }
            {
                union { bf16x8 v; unsigned u[4]; } pk;
                pk.u[0] = cvt2(sa[0][0], sa[0][1]);
                pk.u[1] = cvt2(sa[0][2], sa[0][3]);
                pk.u[2] = cvt2(sa[1][0], sa[1][1]);
                pk.u[3] = cvt2(sa[1][2], sa[1][3]);
                af_a[c] = pk.v;
                pk.u[0] = cvt2(sb[0][0], sb[0][1]);
                pk.u[1] = cvt2(sb[0][2], sb[0][3]);
                pk.u[2] = cvt2(sb[1][0], sb[1][1]);
                pk.u[3] = cvt2(sb[1][2], sb[1][3]);
                af_b[c] = pk.v;
            }
        }

        // ---- PV: each V fragment read feeds both q-sets ----
        __builtin_amdgcn_s_setprio(1);
#pragma unroll
        for (int d = 0; d < 4; ++d) {
#pragma unroll
            for (int c = 0; c < 4; ++c) {
                bf16x8 bv = *(const bf16x8*)&Vtc[(d * 16 + l16) * VSTR + c * 32 + quad * 8];
                o_a[d] = __builtin_amdgcn_mfma_f32_16x16x32_bf16(af_a[c], bv, o_a[d], 0, 0, 0);
                o_b[d] = __builtin_amdgcn_mfma_f32_16x16x32_bf16(af_b[c], bv, o_b[d], 0, 0, 0);
            }
        }
        __builtin_amdgcn_s_setprio(0);

        if (kt + 1 < NT) {   // write-late stage into the other buffer
            unsigned short* Ktn = lds + ((kt + 1) & 1) * BUFW;
            unsigned short* Vtn = Ktn + 128 * KSTR;
#pragma unroll
            for (int i = 0; i < 4; ++i) {
                *(bf16x8*)&Ktn[krow * KSTR + kc + 8 * i] = kr[i];
                *(bf16x8*)&Vtn[vrow * VSTR + vc + 8 * i] = vr[i];
            }
        }
        wm0a = nm0a; wm1a = nm1a; wm0b = nm0b; wm1b = nm1b;
    }

    // l-reduce: sum the 4 quad partials of each q row, then broadcast.
    l_a += __shfl_xor(l_a, 16, 64);
    l_a += __shfl_xor(l_a, 32, 64);
    l_b += __shfl_xor(l_b, 16, 64);
    l_b += __shfl_xor(l_b, 32, 64);

#pragma unroll
    for (int r = 0; r < 4; ++r) {
        const float la = __shfl(l_a, quad * 4 + r, 64);
        const float lb = __shfl(l_b, quad * 4 + r, 64);
        const float ia = 1.0f / fmaxf(la, 1e-30f);
        const float ib = 1.0f / fmaxf(lb, 1e-30f);
        const int qgr = q0 + wave * 16 + quad * 4 + r;
#pragma unroll
        for (int d = 0; d < 4; ++d) {
            out[((size_t)(bz * S_LEN) + qgr) * D_MODEL + h * DH + d * 16 + l16] =
                o_a[d][r] * ia;
            out[((size_t)(bz * S_LEN) + qgr + 64) * D_MODEL + h * DH + d * 16 + l16] =
                o_b[d][r] * ib;
        }
    }
}

// ---------------------------------------------------------------------------
// Single-buffer attention — fallback if >64 KB dynamic LDS opt-in fails,
// and for the small-ws tiers.
// ---------------------------------------------------------------------------
__global__ __launch_bounds__(256) void attn_sb_kernel(
    const unsigned short* __restrict__ ws,
    const unsigned long long* __restrict__ mbits,
    const int* __restrict__ mask,
    float* __restrict__ out, int b_base, int use_bits)
{
    const int h     = blockIdx.x;
    const int qtile = blockIdx.y;
    const int bz    = blockIdx.z;
    const int b0    = b_base + bz;

    const unsigned short* K  = ws + (size_t)bz * KVB_WORDS + (size_t)h * KV_HSTRIDE;
    const unsigned short* Vg = K + WS_V_OFF;
    const unsigned long long* mb = mbits + (size_t)bz * MB_WORDS;

    const int tid  = threadIdx.x;
    const int wave = tid >> 6;
    const int lane = tid & 63;
    const int quad = lane >> 4;
    const int l16  = lane & 15;
    const int q0   = qtile * 128;

    __shared__ __align__(16) unsigned short Vt[64][VSTR];
    __shared__ __align__(16) unsigned short Kt[128 * KSTR];

    bf16x8 aq0a, aq1a, aq0b, aq1b;
    {
        const float* qa =
            out + (size_t)(b0 * S_LEN + q0 + wave * 16 + l16) * D_MODEL + h * DH;
        const float* qb = qa + (size_t)64 * D_MODEL;
        aq0a = cvt8(qa + quad * 8);  aq1a = cvt8(qa + 32 + quad * 8);
        aq0b = cvt8(qb + quad * 8);  aq1b = cvt8(qb + 32 + quad * 8);
    }

    const int qg = q0 + wave * 16 + l16;
    float l_a = 0.f, l_b = 0.f;
    f32x4 o_a[4] = {}, o_b[4] = {};

    const int krow = tid >> 1, kc = (tid & 1) * 32;
    const int vrow = tid >> 2, vc = (tid & 3) * 32;
    bf16x8 kr[4], vr[4];
    {
        const unsigned short* kp = K + (size_t)krow * DH + kc;
        const unsigned short* vp = Vg + (size_t)vrow * S_LEN + vc;
#pragma unroll
        for (int i = 0; i < 4; ++i) {
            kr[i] = *(const bf16x8*)(kp + 8 * i);
            vr[i] = *(const bf16x8*)(vp + 8 * i);
        }
    }

    for (int kt = 0; kt < NT; ++kt) {
#pragma unroll
        for (int i = 0; i < 4; ++i) {
            *(bf16x8*)&Kt[krow * KSTR + kc + 8 * i] = kr[i];
            *(bf16x8*)&Vt[vrow][vc + 8 * i]         = vr[i];
        }
        __syncthreads();

        if (kt + 1 < NT) {
            const unsigned short* kp = K + (size_t)((kt + 1) * KTILE + krow) * DH + kc;
            const unsigned short* vp = Vg + (size_t)vrow * S_LEN + (kt + 1) * KTILE + vc;
#pragma unroll
            for (int i = 0; i < 4; ++i) {
                kr[i] = *(const bf16x8*)(kp + 8 * i);
                vr[i] = *(const bf16x8*)(vp + 8 * i);
            }
        }

        unsigned long long wm0a = 0ull, wm1a = 0ull, wm0b = 0ull, wm1b = 0ull;
        if (use_bits) {
            wm0a = mb[(size_t)(2 * kt) * S_LEN + qg] >> (quad * 4);
            wm1a = mb[(size_t)(2 * kt + 1) * S_LEN + qg] >> (quad * 4);
            wm0b = mb[(size_t)(2 * kt) * S_LEN + qg + 64] >> (quad * 4);
            wm1b = mb[(size_t)(2 * kt + 1) * S_LEN + qg + 64] >> (quad * 4);
        }

        bf16x8 af_a[4], af_b[4];
#pragma unroll
        for (int c = 0; c < 4; ++c) {
            f32x4 sa[2], sb[2];
#pragma unroll
            for (int j = 0; j < 2; ++j) {
                const int blk = 2 * c + j;
                const unsigned short* kb = &Kt[(blk * 16 + l16) * KSTR];
                bf16x8 k0 = *(const bf16x8*)&kb[quad * 8];
                bf16x8 k1 = *(const bf16x8*)&kb[32 + quad * 8];
                f32x4 z = {0.f, 0.f, 0.f, 0.f};
                sa[j] = __builtin_amdgcn_mfma_f32_16x16x32_bf16(k0, aq0a, z, 0, 0, 0);
                sa[j] = __builtin_amdgcn_mfma_f32_16x16x32_bf16(k1, aq1a, sa[j], 0, 0, 0);
                sb[j] = __builtin_amdgcn_mfma_f32_16x16x32_bf16(k0, aq0b, z, 0, 0, 0);
                sb[j] = __builtin_amdgcn_mfma_f32_16x16x32_bf16(k1, aq1b, sb[j], 0, 0, 0);
            }
#pragma unroll
            for (int j = 0; j < 2; ++j) {
                const int blk = 2 * c + j;
                const unsigned long long wa = (blk < 4) ? wm0a : wm1a;
                const unsigned long long wb = (blk < 4) ? wm0b : wm1b;
                const int sh = (blk & 3) * 16;
#pragma unroll
                for (int r = 0; r < 4; ++r) {
                    bool ma, mbk;
                    if (use_bits) {
                        ma  = (wa >> (sh + r)) & 1ull;
                        mbk = (wb >> (sh + r)) & 1ull;
                    } else {
                        const int kg = kt * KTILE + blk * 16 + quad * 4 + r;
                        ma  = mask[((size_t)(b0 * S_LEN) + qg) * S_LEN + kg] != 0;
                        mbk = mask[((size_t)(b0 * S_LEN) + qg + 64) * S_LEN + kg] != 0;
                    }
                    const float pa = ma  ? 0.0f : exp2_fast(sa[j][r]);
                    const float pb = mbk ? 0.0f : exp2_fast(sb[j][r]);
                    sa[j][r] = pa; l_a += pa;
                    sb[j][r] = pb; l_b += pb;
                }
            }
            {
                union { bf16x8 v; unsigned u[4]; } pk;
                pk.u[0] = cvt2(sa[0][0], sa[0][1]);
                pk.u[1] = cvt2(sa[0][2], sa[0][3]);
                pk.u[2] = cvt2(sa[1][0], sa[1][1]);
                pk.u[3] = cvt2(sa[1][2], sa[1][3]);
                af_a[c] = pk.v;
                pk.u[0] = cvt2(sb[0][0], sb[0][1]);
                pk.u[1] = cvt2(sb[0][2], sb[0][3]);
                pk.u[2] = cvt2(sb[1][0], sb[1][1]);
                pk.u[3] = cvt2(sb[1][2], sb[1][3]);
                af_b[c] = pk.v;
            }
        }

#pragma unroll
        for (int d = 0; d < 4; ++d) {
#pragma unroll
            for (int c = 0; c < 4; ++c) {
                bf16x8 bv = *(const bf16x8*)&Vt[d * 16 + l16][c * 32 + quad * 8];
                o_a[d] = __builtin_amdgcn_mfma_f32_16x16x32_bf16(af_a[c], bv, o_a[d], 0, 0, 0);
                o_b[d] = __builtin_amdgcn_mfma_f32_16x16x32_bf16(af_b[c], bv, o_b[d], 0, 0, 0);
            }
        }
        __syncthreads();
    }

    l_a += __shfl_xor(l_a, 16, 64);
    l_a += __shfl_xor(l_a, 32, 64);
    l_b += __shfl_xor(l_b, 16, 64);
    l_b += __shfl_xor(l_b, 32, 64);

#pragma unroll
    for (int r = 0; r < 4; ++r) {
        const float la = __shfl(l_a, quad * 4 + r, 64);
        const float lb = __shfl(l_b, quad * 4 + r, 64);
        const float ia = 1.0f / fmaxf(la, 1e-30f);
        const float ib = 1.0f / fmaxf(lb, 1e-30f);
        const int qgr = q0 + wave * 16 + quad * 4 + r;
#pragma unroll
        for (int d = 0; d < 4; ++d) {
            out[((size_t)(b0 * S_LEN) + qgr) * D_MODEL + h * DH + d * 16 + l16] =
                o_a[d][r] * ia;
            out[((size_t)(b0 * S_LEN) + qgr + 64) * D_MODEL + h * DH + d * 16 + l16] =
                o_b[d][r] * ib;
        }
    }
}

extern "C" void kernel_launch(void* const* d_in, const int* in_sizes, int n_in,
                              void* d_out, int out_size, void* d_ws, size_t ws_size,
                              hipStream_t stream) {
    const float* query = (const float*)d_in[0];
    const float* key   = (const float*)d_in[1];
    const float* value = (const float*)d_in[2];
    const int*   mask  = (const int*)d_in[3];
    const float* Wq    = (const float*)d_in[4];
    const float* bq    = (const float*)d_in[5];
    const float* Wk    = (const float*)d_in[6];
    const float* bk    = (const float*)d_in[7];
    const float* Wv    = (const float*)d_in[8];
    const float* bv    = (const float*)d_in[9];

    unsigned short* ws   = (unsigned short*)d_ws;
    float*          outp = (float*)d_out;

    const size_t KV_BYTES = (size_t)KVB_WORDS * 2;
    const size_t MB_BYTES = (size_t)MB_WORDS * 8;
    const size_t XB_BYTES = (size_t)3 * X_ELEMS * 2;
    const size_t WB_BYTES = (size_t)3 * W_ELEMS * 2;
    const size_t base2    = 2 * KV_BYTES + 2 * MB_BYTES;

    // One-time opt-in for >64 KB dynamic LDS (host-side, graph-capture safe).
    static int db_ok = -1;
    if (db_ok < 0) {
        hipError_t e = hipFuncSetAttribute(
            reinterpret_cast<const void*>(attn_db_kernel),
            hipFuncAttributeMaxDynamicSharedMemorySize, 2 * BUF_BYTES);
        db_ok = (e == hipSuccess) ? 1 : 0;
    }

    if (ws_size >= base2 + XB_BYTES + WB_BYTES) {
        unsigned long long* mbits = (unsigned long long*)(ws + 2 * KVB_WORDS);
        unsigned short* xb = ws + base2 / 2;
        unsigned short* wb = xb + (size_t)3 * X_ELEMS;
        cvt_kernel<<<dim3(1280, 3), 256, 0, stream>>>(
            query, key, value, Wq, Wk, Wv, xb, wb);
        proj_v2_kernel<<<dim3(32, 24), 256, 0, stream>>>(
            xb, wb, bq, bk, bv, outp, ws);
        pack_mask_kernel<<<dim3(2 * MB_WORDS / 4), 256, 0, stream>>>(mask, mbits, 0);
        if (db_ok)
            attn_db_kernel<<<dim3(NH, S_LEN / 128, 2), 256, 2 * BUF_BYTES, stream>>>(
                ws, mbits, outp);
        else
            attn_sb_kernel<<<dim3(NH, S_LEN / 128, 2), 256, 0, stream>>>(
                ws, mbits, mask, outp, 0, 1);
    } else if (ws_size >= base2) {
        unsigned long long* mbits = (unsigned long long*)(ws + 2 * KVB_WORDS);
        proj_fb_kernel<<<dim3(32, 24), 256, 0, stream>>>(
            query, key, value, Wq, bq, Wk, bk, Wv, bv, outp, ws, 0);
        pack_mask_kernel<<<dim3(2 * MB_WORDS / 4), 256, 0, stream>>>(mask, mbits, 0);
        if (db_ok)
            attn_db_kernel<<<dim3(NH, S_LEN / 128, 2), 256, 2 * BUF_BYTES, stream>>>(
                ws, mbits, outp);
        else
            attn_sb_kernel<<<dim3(NH, S_LEN / 128, 2), 256, 0, stream>>>(
                ws, mbits, mask, outp, 0, 1);
    } else if (ws_size >= KV_BYTES + MB_BYTES) {
        unsigned long long* mbits = (unsigned long long*)(ws + KVB_WORDS);
        for (int b0 = 0; b0 < BATCH; ++b0) {
            proj_fb_kernel<<<dim3(16, 24), 256, 0, stream>>>(
                query, key, value, Wq, bq, Wk, bk, Wv, bv, outp, ws, b0);
            pack_mask_kernel<<<dim3(MB_WORDS / 4), 256, 0, stream>>>(mask, mbits, b0);
            attn_sb_kernel<<<dim3(NH, S_LEN / 128, 1), 256, 0, stream>>>(
                ws, mbits, mask, outp, b0, 1);
        }
    } else {
        for (int b0 = 0; b0 < BATCH; ++b0) {
            proj_fb_kernel<<<dim3(16, 24), 256, 0, stream>>>(
                query, key, value, Wq, bq, Wk, bk, Wv, bv, outp, ws, b0);
            attn_sb_kernel<<<dim3(NH, S_LEN / 128, 1), 256, 0, stream>>>(
                ws, (const unsigned long long*)ws, mask, outp, b0, 0);
        }
    }
}